// Round 2
// baseline (620.269 us; speedup 1.0000x reference)
//
#include <hip/hip_runtime.h>
#include <hip/hip_bf16.h>
#include <stdint.h>

// ---------------------------------------------------------------------------
// QuantQwenMLP: W4A8 fake-quant SwiGLU MLP.
//   B=4 S=2048 H=2048 I=5632  -> M = B*S = 8192 tokens
//   gate = (int8 x) @ (int4 Wg)^T * scales ; up likewise ; h = silu(g)*u
//   out  = (int8 h) @ (int4 Wd)^T * scales
// Integer accumulation is exact via v_mfma_i32_16x16x64_i8, so the only
// deviation from the fp32 reference is silu/mul rounding.
//
// R1 -> R2: chunk the M dimension adaptively so the workspace footprint
// fits ws_size (R1 assumed 282 MB of scratch; likely OOB -> device fault).
// ---------------------------------------------------------------------------

typedef int i32x4 __attribute__((ext_vector_type(4)));

#define BM 128
#define BN 128
#define BK 64

__device__ __forceinline__ void load_lds16(const void* g, void* l) {
    __builtin_amdgcn_global_load_lds(
        (const __attribute__((address_space(1))) unsigned int*)g,
        (__attribute__((address_space(3))) unsigned int*)l,
        16, 0, 0);
}

// ---------------------------------------------------------------------------
// Per-row symmetric fake-quant: scale = max(amax/qmax, 1e-8); q = clip(rint(v/scale))
// One block per row; row cached in LDS so we read global only once.
// C4 = row length / 4 (row length divisible by 4 for all our shapes).
// ---------------------------------------------------------------------------
__global__ __launch_bounds__(256) void quant_rows(
    const float* __restrict__ src, int8_t* __restrict__ dst,
    float* __restrict__ scales, int C4, float qmax)
{
    __shared__ float4 buf[1408];        // up to 5632 floats = 22.5 KB
    __shared__ float wmax[4];
    const int r = blockIdx.x;
    const float4* s4 = (const float4*)src + (long)r * C4;

    float am = 0.f;
    for (int i = threadIdx.x; i < C4; i += 256) {
        float4 v = s4[i];
        buf[i] = v;
        am = fmaxf(am, fmaxf(fmaxf(fabsf(v.x), fabsf(v.y)),
                             fmaxf(fabsf(v.z), fabsf(v.w))));
    }
    #pragma unroll
    for (int off = 32; off; off >>= 1)
        am = fmaxf(am, __shfl_xor(am, off));
    if ((threadIdx.x & 63) == 0) wmax[threadIdx.x >> 6] = am;
    __syncthreads();
    const float amax = fmaxf(fmaxf(wmax[0], wmax[1]), fmaxf(wmax[2], wmax[3]));
    const float scale = fmaxf(amax / qmax, 1e-8f);
    if (threadIdx.x == 0) scales[r] = scale;

    char4* d4 = (char4*)dst + (long)r * C4;
    for (int i = threadIdx.x; i < C4; i += 256) {
        float4 v = buf[i];
        char4 q;
        q.x = (signed char)(int)fminf(fmaxf(rintf(v.x / scale), -qmax), qmax);
        q.y = (signed char)(int)fminf(fmaxf(rintf(v.y / scale), -qmax), qmax);
        q.z = (signed char)(int)fminf(fmaxf(rintf(v.z / scale), -qmax), qmax);
        q.w = (signed char)(int)fminf(fmaxf(rintf(v.w / scale), -qmax), qmax);
        d4[i] = q;
    }
}

// ---------------------------------------------------------------------------
// Staging helper: tile is [128 rows][64 bytes] of int8, 512 16-B chunks.
// LDS chunk (row, c) holds global chunk (row, c ^ (row&3)) -- XOR swizzle
// keeps global loads fully coalesced (permutes within each 64-B row) while
// reducing ds_read_b128 bank conflicts.
// ---------------------------------------------------------------------------
__device__ __forceinline__ void stage_tile(
    const int8_t* __restrict__ gbase, long row0, int K, int k0,
    int8_t* ldst, int tid)
{
    #pragma unroll
    for (int j = 0; j < 2; ++j) {
        int cL  = tid + j * 256;
        int row = cL >> 2;
        int c   = cL & 3;
        int cs  = c ^ (row & 3);
        load_lds16(gbase + (row0 + row) * (long)K + k0 + cs * 16,
                   ldst + cL * 16);
    }
}

// ---------------------------------------------------------------------------
// Fused gate+up int8 GEMM with SwiGLU epilogue.
// A: [M][K] int8 (per-row scale sA), Bg/Bu: [N][K] int8 (per-row scales).
// H[m][n] = silu(gacc*sA*sBg) * (uacc*sA*sBu),  fp32.
// ---------------------------------------------------------------------------
__global__ __launch_bounds__(256, 2) void gemm_dual(
    const int8_t* __restrict__ Aq, const float* __restrict__ sA,
    const int8_t* __restrict__ Bg, const float* __restrict__ sBg,
    const int8_t* __restrict__ Bu, const float* __restrict__ sBu,
    float* __restrict__ H, int M, int N, int K)
{
    __shared__ int8_t lds[3 * BM * BK];     // 24 KB
    int8_t* ldsA = lds;
    int8_t* ldsG = lds + BM * BK;
    int8_t* ldsU = lds + 2 * BM * BK;

    const int tid  = threadIdx.x;
    const int lane = tid & 63;
    const int wave = tid >> 6;
    const int wm = (wave >> 1) * 64;
    const int wn = (wave & 1) * 64;
    const long m0 = (long)blockIdx.y * BM;
    const long n0 = (long)blockIdx.x * BN;

    i32x4 accg[4][4], accu[4][4];
    #pragma unroll
    for (int i = 0; i < 4; ++i)
        #pragma unroll
        for (int j = 0; j < 4; ++j) {
            accg[i][j] = i32x4{0, 0, 0, 0};
            accu[i][j] = i32x4{0, 0, 0, 0};
        }

    const int mrow = lane & 15;
    const int kq   = lane >> 4;     // which 16-B chunk along BK

    for (int k0 = 0; k0 < K; k0 += BK) {
        stage_tile(Aq, m0, K, k0, ldsA, tid);
        stage_tile(Bg, n0, K, k0, ldsG, tid);
        stage_tile(Bu, n0, K, k0, ldsU, tid);
        __syncthreads();

        i32x4 af[4], gf[4], uf[4];
        #pragma unroll
        for (int i = 0; i < 4; ++i) {
            int rA = wm + i * 16 + mrow;
            af[i] = *(const i32x4*)(ldsA + rA * 64 + (kq ^ (rA & 3)) * 16);
            int rB = wn + i * 16 + mrow;
            gf[i] = *(const i32x4*)(ldsG + rB * 64 + (kq ^ (rB & 3)) * 16);
            uf[i] = *(const i32x4*)(ldsU + rB * 64 + (kq ^ (rB & 3)) * 16);
        }
        #pragma unroll
        for (int mi = 0; mi < 4; ++mi)
            #pragma unroll
            for (int ni = 0; ni < 4; ++ni) {
                accg[mi][ni] = __builtin_amdgcn_mfma_i32_16x16x64_i8(af[mi], gf[ni], accg[mi][ni], 0, 0, 0);
                accu[mi][ni] = __builtin_amdgcn_mfma_i32_16x16x64_i8(af[mi], uf[ni], accu[mi][ni], 0, 0, 0);
            }
        __syncthreads();
    }

    // Epilogue. C/D layout: col = lane&15, row = (lane>>4)*4 + reg.
    const int cn = lane & 15;
    const int cr = (lane >> 4) * 4;
    float sg[4], su[4];
    #pragma unroll
    for (int ni = 0; ni < 4; ++ni) {
        long n = n0 + wn + ni * 16 + cn;
        sg[ni] = sBg[n];
        su[ni] = sBu[n];
    }
    #pragma unroll
    for (int mi = 0; mi < 4; ++mi) {
        #pragma unroll
        for (int r = 0; r < 4; ++r) {
            long m = m0 + wm + mi * 16 + cr + r;
            float sa = sA[m];
            #pragma unroll
            for (int ni = 0; ni < 4; ++ni) {
                long n = n0 + wn + ni * 16 + cn;
                float g = (float)accg[mi][ni][r] * sa * sg[ni];
                float u = (float)accu[mi][ni][r] * sa * su[ni];
                float hv = g / (1.f + __expf(-g)) * u;
                H[m * N + n] = hv;
            }
        }
    }
}

// ---------------------------------------------------------------------------
// Single int8 GEMM with scale epilogue: out[m][n] = acc * sA[m] * sB[n].
// ---------------------------------------------------------------------------
__global__ __launch_bounds__(256, 2) void gemm_single(
    const int8_t* __restrict__ Aq, const float* __restrict__ sA,
    const int8_t* __restrict__ Bq, const float* __restrict__ sB,
    float* __restrict__ O, int M, int N, int K)
{
    __shared__ int8_t lds[2 * BM * BK];     // 16 KB
    int8_t* ldsA = lds;
    int8_t* ldsB = lds + BM * BK;

    const int tid  = threadIdx.x;
    const int lane = tid & 63;
    const int wave = tid >> 6;
    const int wm = (wave >> 1) * 64;
    const int wn = (wave & 1) * 64;
    const long m0 = (long)blockIdx.y * BM;
    const long n0 = (long)blockIdx.x * BN;

    i32x4 acc[4][4];
    #pragma unroll
    for (int i = 0; i < 4; ++i)
        #pragma unroll
        for (int j = 0; j < 4; ++j) acc[i][j] = i32x4{0, 0, 0, 0};

    const int mrow = lane & 15;
    const int kq   = lane >> 4;

    for (int k0 = 0; k0 < K; k0 += BK) {
        stage_tile(Aq, m0, K, k0, ldsA, tid);
        stage_tile(Bq, n0, K, k0, ldsB, tid);
        __syncthreads();

        i32x4 af[4], bf[4];
        #pragma unroll
        for (int i = 0; i < 4; ++i) {
            int rA = wm + i * 16 + mrow;
            af[i] = *(const i32x4*)(ldsA + rA * 64 + (kq ^ (rA & 3)) * 16);
            int rB = wn + i * 16 + mrow;
            bf[i] = *(const i32x4*)(ldsB + rB * 64 + (kq ^ (rB & 3)) * 16);
        }
        #pragma unroll
        for (int mi = 0; mi < 4; ++mi)
            #pragma unroll
            for (int ni = 0; ni < 4; ++ni)
                acc[mi][ni] = __builtin_amdgcn_mfma_i32_16x16x64_i8(af[mi], bf[ni], acc[mi][ni], 0, 0, 0);
        __syncthreads();
    }

    const int cn = lane & 15;
    const int cr = (lane >> 4) * 4;
    float sb[4];
    #pragma unroll
    for (int ni = 0; ni < 4; ++ni) sb[ni] = sB[n0 + wn + ni * 16 + cn];
    #pragma unroll
    for (int mi = 0; mi < 4; ++mi) {
        #pragma unroll
        for (int r = 0; r < 4; ++r) {
            long m = m0 + wm + mi * 16 + cr + r;
            float sa = sA[m];
            #pragma unroll
            for (int ni = 0; ni < 4; ++ni) {
                long n = n0 + wn + ni * 16 + cn;
                O[m * N + n] = (float)acc[mi][ni][r] * sa * sb[ni];
            }
        }
    }
}

// ---------------------------------------------------------------------------

extern "C" void kernel_launch(void* const* d_in, const int* in_sizes, int n_in,
                              void* d_out, int out_size, void* d_ws, size_t ws_size,
                              hipStream_t stream)
{
    const float* x  = (const float*)d_in[0];   // [4,2048,2048]
    const float* Wg = (const float*)d_in[1];   // [5632,2048]
    const float* Wu = (const float*)d_in[2];   // [5632,2048]
    const float* Wd = (const float*)d_in[3];   // [2048,5632]
    float* out = (float*)d_out;                // [4,2048,2048] fp32

    const int M  = 8192;      // B*S
    const int H  = 2048;
    const int I  = 5632;

    // ---- fixed workspace regions (~49.1 MiB, all 256-B aligned sizes) ----
    char* p = (char*)d_ws;
    int8_t* xq  = (int8_t*)p; p += (size_t)M * H;            // 16.78 MB
    float*  sx  = (float*)p;  p += (size_t)M * 4;
    int8_t* wgq = (int8_t*)p; p += (size_t)I * H;            // 11.53 MB
    float*  swg = (float*)p;  p += (size_t)I * 4;
    int8_t* wuq = (int8_t*)p; p += (size_t)I * H;            // 11.53 MB
    float*  swu = (float*)p;  p += (size_t)I * 4;
    int8_t* wdq = (int8_t*)p; p += (size_t)H * I;            // 11.53 MB
    float*  swd = (float*)p;  p += (size_t)H * 4;
    float*  sh  = (float*)p;  p += (size_t)M * 4;            // full-M h scales
    const size_t fixed_bytes = (size_t)(p - (char*)d_ws);

    // ---- pick largest M-chunk whose h (fp32) + hq (int8) fit ws_size ----
    // variable bytes = Mc * I * 5
    int Mc = 256;
    for (int cand = 8192; cand >= 256; cand >>= 1) {
        size_t need = fixed_bytes + (size_t)cand * I * 5;
        if (need <= ws_size) { Mc = cand; break; }
    }
    float*  hbuf = (float*)p;  p += (size_t)Mc * I * 4;
    int8_t* hq   = (int8_t*)p;

    // 1) quantize weights (qmax=7) and activations (qmax=127)
    quant_rows<<<I, 256, 0, stream>>>(Wg, wgq, swg, H / 4, 7.f);
    quant_rows<<<I, 256, 0, stream>>>(Wu, wuq, swu, H / 4, 7.f);
    quant_rows<<<H, 256, 0, stream>>>(Wd, wdq, swd, I / 4, 7.f);
    quant_rows<<<M, 256, 0, stream>>>(x,  xq,  sx,  H / 4, 127.f);

    // 2) per M-chunk: gate+up GEMM + SwiGLU -> h ; quantize h ; down-proj
    for (int m0 = 0; m0 < M; m0 += Mc) {
        gemm_dual<<<dim3(I / BN, Mc / BM), 256, 0, stream>>>(
            xq + (size_t)m0 * H, sx + m0, wgq, swg, wuq, swu,
            hbuf, Mc, I, H);
        quant_rows<<<Mc, 256, 0, stream>>>(hbuf, hq, sh + m0, I / 4, 127.f);
        gemm_single<<<dim3(H / BN, Mc / BM), 256, 0, stream>>>(
            hq, sh + m0, wdq, swd, out + (size_t)m0 * H, Mc, H, I);
    }
}

// Round 3
// 609.870 us; speedup vs baseline: 1.0171x; 1.0171x over previous
//
#include <hip/hip_runtime.h>
#include <hip/hip_bf16.h>
#include <stdint.h>

// ---------------------------------------------------------------------------
// QuantQwenMLP: W4A8 fake-quant SwiGLU MLP.
//   B=4 S=2048 H=2048 I=5632  -> M = B*S = 8192 tokens
// R2 -> R3: 32x32x32 i8 MFMA (+14% matrix-pipe ceiling), BK=128 (half the
// barriers; we're VGPR-limited to 2 blocks/CU so the LDS growth is free),
// full-range LDS chunk swizzle (8->4-way bank conflicts), expf in SwiGLU.
// ---------------------------------------------------------------------------

typedef int i32x4  __attribute__((ext_vector_type(4)));
typedef int i32x16 __attribute__((ext_vector_type(16)));

#define BM 128
#define BN 128
#define BK 128      // bytes along K per LDS tile

__device__ __forceinline__ void load_lds16(const void* g, void* l) {
    __builtin_amdgcn_global_load_lds(
        (const __attribute__((address_space(1))) unsigned int*)g,
        (__attribute__((address_space(3))) unsigned int*)l,
        16, 0, 0);
}

// ---------------------------------------------------------------------------
// Per-row symmetric fake-quant: scale = max(amax/qmax, 1e-8); q = clip(rint(v/scale))
// One block per row; row cached in LDS so global is read once.
// ---------------------------------------------------------------------------
__global__ __launch_bounds__(256) void quant_rows(
    const float* __restrict__ src, int8_t* __restrict__ dst,
    float* __restrict__ scales, int C4, float qmax)
{
    __shared__ float4 buf[1408];        // up to 5632 floats = 22.5 KB
    __shared__ float wmax[4];
    const int r = blockIdx.x;
    const float4* s4 = (const float4*)src + (long)r * C4;

    float am = 0.f;
    for (int i = threadIdx.x; i < C4; i += 256) {
        float4 v = s4[i];
        buf[i] = v;
        am = fmaxf(am, fmaxf(fmaxf(fabsf(v.x), fabsf(v.y)),
                             fmaxf(fabsf(v.z), fabsf(v.w))));
    }
    #pragma unroll
    for (int off = 32; off; off >>= 1)
        am = fmaxf(am, __shfl_xor(am, off));
    if ((threadIdx.x & 63) == 0) wmax[threadIdx.x >> 6] = am;
    __syncthreads();
    const float amax = fmaxf(fmaxf(wmax[0], wmax[1]), fmaxf(wmax[2], wmax[3]));
    const float scale = fmaxf(amax / qmax, 1e-8f);
    if (threadIdx.x == 0) scales[r] = scale;

    char4* d4 = (char4*)dst + (long)r * C4;
    for (int i = threadIdx.x; i < C4; i += 256) {
        float4 v = buf[i];
        char4 q;
        q.x = (signed char)(int)fminf(fmaxf(rintf(v.x / scale), -qmax), qmax);
        q.y = (signed char)(int)fminf(fmaxf(rintf(v.y / scale), -qmax), qmax);
        q.z = (signed char)(int)fminf(fmaxf(rintf(v.z / scale), -qmax), qmax);
        q.w = (signed char)(int)fminf(fmaxf(rintf(v.w / scale), -qmax), qmax);
        d4[i] = q;
    }
}

// ---------------------------------------------------------------------------
// Stage a [128 rows][128 B] int8 tile: 1024 16-B chunks, 4 per thread.
// LDS slot (row, c) holds global chunk (row, c ^ (row&7)).  With 128-B rows
// every row starts at bank 0, so the chunk XOR alone spreads fragment reads
// across all 8 bank groups.  Global side: 8 lanes cover one row's 8 chunks
// (permuted) -> still one 128-B coalesced segment.  LDS dst = base + lane*16
// as global_load_lds requires.
// ---------------------------------------------------------------------------
__device__ __forceinline__ void stage_tile(
    const int8_t* __restrict__ gbase, long row0, int K, int k0,
    int8_t* ldst, int tid)
{
    #pragma unroll
    for (int j = 0; j < 4; ++j) {
        int cL  = tid + j * 256;
        int row = cL >> 3;
        int c   = cL & 7;
        int cs  = c ^ (row & 7);
        load_lds16(gbase + (row0 + row) * (long)K + k0 + cs * 16,
                   ldst + cL * 16);
    }
}

// Read a 32x32x32 A/B fragment: rows rowbase..rowbase+31 (row = rowbase + (lane&31)),
// K-chunk q = ks*2 + (lane>>5), stored at swizzled slot q ^ (row&7).
__device__ __forceinline__ i32x4 read_frag(const int8_t* lds, int rowbase,
                                           int cl, int kq, int ks)
{
    int row = rowbase + cl;
    int slot = (ks * 2 + kq) ^ (row & 7);
    return *(const i32x4*)(lds + row * BK + slot * 16);
}

// ---------------------------------------------------------------------------
// Fused gate+up int8 GEMM with SwiGLU epilogue (fp32 H out).
// ---------------------------------------------------------------------------
__global__ __launch_bounds__(256, 2) void gemm_dual(
    const int8_t* __restrict__ Aq, const float* __restrict__ sA,
    const int8_t* __restrict__ Bg, const float* __restrict__ sBg,
    const int8_t* __restrict__ Bu, const float* __restrict__ sBu,
    float* __restrict__ H, int M, int N, int K)
{
    __shared__ int8_t lds[3 * BM * BK];     // 48 KB
    int8_t* ldsA = lds;
    int8_t* ldsG = lds + BM * BK;
    int8_t* ldsU = lds + 2 * BM * BK;

    const int tid  = threadIdx.x;
    const int lane = tid & 63;
    const int wave = tid >> 6;
    const int wm = (wave >> 1) * 64;    // wave's 64x64 quadrant
    const int wn = (wave & 1) * 64;
    const long m0 = (long)blockIdx.y * BM;
    const long n0 = (long)blockIdx.x * BN;

    i32x16 accg[2][2], accu[2][2];
    #pragma unroll
    for (int i = 0; i < 2; ++i)
        #pragma unroll
        for (int j = 0; j < 2; ++j) {
            accg[i][j] = i32x16{0,0,0,0,0,0,0,0,0,0,0,0,0,0,0,0};
            accu[i][j] = i32x16{0,0,0,0,0,0,0,0,0,0,0,0,0,0,0,0};
        }

    const int cl = lane & 31;
    const int kq = lane >> 5;

    for (int k0 = 0; k0 < K; k0 += BK) {
        stage_tile(Aq, m0, K, k0, ldsA, tid);
        stage_tile(Bg, n0, K, k0, ldsG, tid);
        stage_tile(Bu, n0, K, k0, ldsU, tid);
        __syncthreads();

        #pragma unroll
        for (int ks = 0; ks < 4; ++ks) {
            i32x4 a0 = read_frag(ldsA, wm,      cl, kq, ks);
            i32x4 a1 = read_frag(ldsA, wm + 32, cl, kq, ks);
            i32x4 g0 = read_frag(ldsG, wn,      cl, kq, ks);
            i32x4 g1 = read_frag(ldsG, wn + 32, cl, kq, ks);
            i32x4 u0 = read_frag(ldsU, wn,      cl, kq, ks);
            i32x4 u1 = read_frag(ldsU, wn + 32, cl, kq, ks);
            accg[0][0] = __builtin_amdgcn_mfma_i32_32x32x32_i8(a0, g0, accg[0][0], 0, 0, 0);
            accg[0][1] = __builtin_amdgcn_mfma_i32_32x32x32_i8(a0, g1, accg[0][1], 0, 0, 0);
            accg[1][0] = __builtin_amdgcn_mfma_i32_32x32x32_i8(a1, g0, accg[1][0], 0, 0, 0);
            accg[1][1] = __builtin_amdgcn_mfma_i32_32x32x32_i8(a1, g1, accg[1][1], 0, 0, 0);
            accu[0][0] = __builtin_amdgcn_mfma_i32_32x32x32_i8(a0, u0, accu[0][0], 0, 0, 0);
            accu[0][1] = __builtin_amdgcn_mfma_i32_32x32x32_i8(a0, u1, accu[0][1], 0, 0, 0);
            accu[1][0] = __builtin_amdgcn_mfma_i32_32x32x32_i8(a1, u0, accu[1][0], 0, 0, 0);
            accu[1][1] = __builtin_amdgcn_mfma_i32_32x32x32_i8(a1, u1, accu[1][1], 0, 0, 0);
        }
        __syncthreads();
    }

    // Epilogue. 32x32 C/D layout: col = lane&31, row = (reg&3) + 8*(reg>>2) + 4*(lane>>5).
    float sg[2], su[2];
    #pragma unroll
    for (int ni = 0; ni < 2; ++ni) {
        long n = n0 + wn + ni * 32 + cl;
        sg[ni] = sBg[n];
        su[ni] = sBu[n];
    }
    #pragma unroll
    for (int mi = 0; mi < 2; ++mi) {
        #pragma unroll
        for (int reg = 0; reg < 16; ++reg) {
            long m = m0 + wm + mi * 32 + (reg & 3) + 8 * (reg >> 2) + 4 * kq;
            float sa = sA[m];
            #pragma unroll
            for (int ni = 0; ni < 2; ++ni) {
                long n = n0 + wn + ni * 32 + cl;
                float g = (float)accg[mi][ni][reg] * sa * sg[ni];
                float u = (float)accu[mi][ni][reg] * sa * su[ni];
                float s = 1.f / (1.f + expf(-g));
                H[m * N + n] = (g * s) * u;
            }
        }
    }
}

// ---------------------------------------------------------------------------
// Single int8 GEMM: out[m][n] = acc * sA[m] * sB[n].
// ---------------------------------------------------------------------------
__global__ __launch_bounds__(256, 2) void gemm_single(
    const int8_t* __restrict__ Aq, const float* __restrict__ sA,
    const int8_t* __restrict__ Bq, const float* __restrict__ sB,
    float* __restrict__ O, int M, int N, int K)
{
    __shared__ int8_t lds[2 * BM * BK];     // 32 KB
    int8_t* ldsA = lds;
    int8_t* ldsB = lds + BM * BK;

    const int tid  = threadIdx.x;
    const int lane = tid & 63;
    const int wave = tid >> 6;
    const int wm = (wave >> 1) * 64;
    const int wn = (wave & 1) * 64;
    const long m0 = (long)blockIdx.y * BM;
    const long n0 = (long)blockIdx.x * BN;

    i32x16 acc[2][2];
    #pragma unroll
    for (int i = 0; i < 2; ++i)
        #pragma unroll
        for (int j = 0; j < 2; ++j)
            acc[i][j] = i32x16{0,0,0,0,0,0,0,0,0,0,0,0,0,0,0,0};

    const int cl = lane & 31;
    const int kq = lane >> 5;

    for (int k0 = 0; k0 < K; k0 += BK) {
        stage_tile(Aq, m0, K, k0, ldsA, tid);
        stage_tile(Bq, n0, K, k0, ldsB, tid);
        __syncthreads();

        #pragma unroll
        for (int ks = 0; ks < 4; ++ks) {
            i32x4 a0 = read_frag(ldsA, wm,      cl, kq, ks);
            i32x4 a1 = read_frag(ldsA, wm + 32, cl, kq, ks);
            i32x4 b0 = read_frag(ldsB, wn,      cl, kq, ks);
            i32x4 b1 = read_frag(ldsB, wn + 32, cl, kq, ks);
            acc[0][0] = __builtin_amdgcn_mfma_i32_32x32x32_i8(a0, b0, acc[0][0], 0, 0, 0);
            acc[0][1] = __builtin_amdgcn_mfma_i32_32x32x32_i8(a0, b1, acc[0][1], 0, 0, 0);
            acc[1][0] = __builtin_amdgcn_mfma_i32_32x32x32_i8(a1, b0, acc[1][0], 0, 0, 0);
            acc[1][1] = __builtin_amdgcn_mfma_i32_32x32x32_i8(a1, b1, acc[1][1], 0, 0, 0);
        }
        __syncthreads();
    }

    float sb[2];
    #pragma unroll
    for (int ni = 0; ni < 2; ++ni) sb[ni] = sB[n0 + wn + ni * 32 + cl];
    #pragma unroll
    for (int mi = 0; mi < 2; ++mi) {
        #pragma unroll
        for (int reg = 0; reg < 16; ++reg) {
            long m = m0 + wm + mi * 32 + (reg & 3) + 8 * (reg >> 2) + 4 * kq;
            float sa = sA[m];
            #pragma unroll
            for (int ni = 0; ni < 2; ++ni) {
                long n = n0 + wn + ni * 32 + cl;
                O[m * N + n] = (float)acc[mi][ni][reg] * sa * sb[ni];
            }
        }
    }
}

// ---------------------------------------------------------------------------

extern "C" void kernel_launch(void* const* d_in, const int* in_sizes, int n_in,
                              void* d_out, int out_size, void* d_ws, size_t ws_size,
                              hipStream_t stream)
{
    const float* x  = (const float*)d_in[0];   // [4,2048,2048]
    const float* Wg = (const float*)d_in[1];   // [5632,2048]
    const float* Wu = (const float*)d_in[2];   // [5632,2048]
    const float* Wd = (const float*)d_in[3];   // [2048,5632]
    float* out = (float*)d_out;                // [4,2048,2048] fp32

    const int M  = 8192;      // B*S
    const int H  = 2048;
    const int I  = 5632;

    // ---- fixed workspace regions (~49.1 MiB) ----
    char* p = (char*)d_ws;
    int8_t* xq  = (int8_t*)p; p += (size_t)M * H;
    float*  sx  = (float*)p;  p += (size_t)M * 4;
    int8_t* wgq = (int8_t*)p; p += (size_t)I * H;
    float*  swg = (float*)p;  p += (size_t)I * 4;
    int8_t* wuq = (int8_t*)p; p += (size_t)I * H;
    float*  swu = (float*)p;  p += (size_t)I * 4;
    int8_t* wdq = (int8_t*)p; p += (size_t)H * I;
    float*  swd = (float*)p;  p += (size_t)H * 4;
    float*  sh  = (float*)p;  p += (size_t)M * 4;
    const size_t fixed_bytes = (size_t)(p - (char*)d_ws);

    // ---- largest M-chunk whose h (fp32) + hq (int8) fit ws_size ----
    int Mc = 256;
    for (int cand = 8192; cand >= 256; cand >>= 1) {
        size_t need = fixed_bytes + (size_t)cand * I * 5;
        if (need <= ws_size) { Mc = cand; break; }
    }
    float*  hbuf = (float*)p;  p += (size_t)Mc * I * 4;
    int8_t* hq   = (int8_t*)p;

    // 1) quantize weights (qmax=7) and activations (qmax=127)
    quant_rows<<<I, 256, 0, stream>>>(Wg, wgq, swg, H / 4, 7.f);
    quant_rows<<<I, 256, 0, stream>>>(Wu, wuq, swu, H / 4, 7.f);
    quant_rows<<<H, 256, 0, stream>>>(Wd, wdq, swd, I / 4, 7.f);
    quant_rows<<<M, 256, 0, stream>>>(x,  xq,  sx,  H / 4, 127.f);

    // 2) per M-chunk: gate+up GEMM + SwiGLU -> h ; quantize h ; down-proj
    for (int m0 = 0; m0 < M; m0 += Mc) {
        gemm_dual<<<dim3(I / BN, Mc / BM), 256, 0, stream>>>(
            xq + (size_t)m0 * H, sx + m0, wgq, swg, wuq, swu,
            hbuf, Mc, I, H);
        quant_rows<<<Mc, 256, 0, stream>>>(hbuf, hq, sh + m0, I / 4, 127.f);
        gemm_single<<<dim3(H / BN, Mc / BM), 256, 0, stream>>>(
            hq, sh + m0, wdq, swd, out + (size_t)m0 * H, Mc, H, I);
    }
}